// Round 8
// baseline (31.774 us; speedup 1.0000x reference)
//
#include <hip/hip_runtime.h>

// GD_lagrange_multi fused kernel for MI355X (gfx950).  Round 8: broadcast
// lam-reduce (reducer wave) + 2-barrier pipelined schedule + prologue overlap.
// Shapes: W=4, B=32, S=16, G=1024. One block per (w,b): 8 waves, wave owns
// 128 g-rows = 8 MFMA tiles (16x16x16 f16, f32 accum).
//
// Lane layout (per tile), lane l = 16q + m:
//   Om[t]  r = Omega[g0+16t+4q+r][j=m]   (C/D layout, f32 master)
//   OmB[t] e = Omega[g0+16t+4q+e][j=m]   (B-frag, k=g)
//   YpB[t] e = Yp[i=m][g0+16t+4q+e]      (A-frag, k=g)
//   YpA[t] e = Yp[s=4q+e][g0+16t+m]      (A-frag, k=s)
//   lamN_B e = (-mu*lam)[s=4q+e][j=m]    (B-frag, k=s)
//
// Per-iteration schedule (i produces Om_{i+1}):
//   HOT : Om_{i+1} = mfma(YpA, lamN_i, C=OmPre_i); pack; phaseB partial
//         P=Yp@Om_{i+1} (2 chains); ds_write partial[wv]          -> barrier1
//   GAP : wv0: read 8 partials, gsum, delta_{i+1}=gsum-tgt,
//              lamN_{i+2}=lamN_{i+1}+K*delta_{i+1}, write slot i&1
//         all: OmPre_{i+1} = norm-fold(Om_{i+1})  (3 MFMA/tile)   -> barrier2
//   TAIL: non-wv0 read slot (i+1)&1 = lamN_{i+1} (written gap_{i-1});
//         wv0 packs its in-reg master.  1-deep lamN pipeline; slot
//         parity race-free: reads/writes always barrier-separated.
// Reference semantics preserved exactly: lam update uses OLD Omega,
// Omega update uses OLD lam.

typedef float    f32x4 __attribute__((ext_vector_type(4)));
typedef _Float16 f16x4 __attribute__((ext_vector_type(4)));
typedef __fp16   h16x2 __attribute__((ext_vector_type(2)));

#define MUv 1e-3f
#define ROv 1e-3f

__device__ __forceinline__ f16x4 pack4(float a, float b, float c, float d) {
  h16x2 lo = __builtin_amdgcn_cvt_pkrtz(a, b);
  h16x2 hi = __builtin_amdgcn_cvt_pkrtz(c, d);
  union { struct { h16x2 lo, hi; } p; f16x4 v; } u;
  u.p.lo = lo; u.p.hi = hi;
  return u.v;
}

__device__ __forceinline__ f16x4 pack_dup(float a) {
  h16x2 d = __builtin_amdgcn_cvt_pkrtz(a, a);
  union { struct { h16x2 lo, hi; } p; f16x4 v; } u;
  u.p.lo = d; u.p.hi = d;
  return u.v;
}

__global__ __launch_bounds__(512) void gd_lagrange_kernel(
    const float* __restrict__ Yp,   // [128][16][1024]
    const float* __restrict__ Uk,   // [128][16][16]
    const float* __restrict__ Lm,   // [128][16][16]
    const float* __restrict__ Om0,  // [128][1024][16]
    const int* __restrict__ nitp,   // [1]
    float* __restrict__ out) {      // [128][1024][16]
  constexpr int S = 16, G = 1024;
  constexpr int YP_LD = 1028;

  const int wb   = blockIdx.x;
  const int tid  = threadIdx.x;
  const int wv   = tid >> 6;
  const int lane = tid & 63;
  const int q    = (tid >> 4) & 3;
  const int m    = tid & 15;
  const int g0   = wv * 128;

  __shared__ float ldsYp[S * YP_LD];   // dead after prologue
  __shared__ float ldsRed[8][256];     // per-wave partial, lane-contiguous b128
  __shared__ float ldsLam[2][256];     // lamN broadcast slots (parity-pipelined)
  __shared__ float ldsUk[256];
  __shared__ float ldsLm[256];

  const float* ypg = Yp + (size_t)wb * (S * G);
  const float* omg = Om0 + (size_t)wb * (G * S);

  // ---- Om master loads FIRST (HBM latency overlaps Yp staging below) ----
  f32x4 Om[8];
  #pragma unroll
  for (int t = 0; t < 8; ++t)
    #pragma unroll
    for (int r = 0; r < 4; ++r)
      Om[t][r] = omg[(g0 + 16 * t + 4 * q + r) * S + m];

  // ---- stage Yp slice ----
  #pragma unroll
  for (int k = 0; k < 8; ++k) {
    int vi  = k * 512 + tid;
    f32x4 v = ((const f32x4*)ypg)[vi];
    int row = vi >> 8;
    int col = (vi & 255) * 4;
    *(f32x4*)&ldsYp[row * YP_LD + col] = v;
  }
  if (tid < 256) ldsUk[tid] = Uk[wb * 256 + tid];
  else           ldsLm[tid - 256] = Lm[wb * 256 + tid - 256];
  __syncthreads();

  // ---- static frags ----
  f16x4 Ifrag, ones1;
  #pragma unroll
  for (int e = 0; e < 4; ++e) {
    Ifrag[e] = (4 * q + e == m) ? (_Float16)1.0f : (_Float16)0.0f;
    ones1[e] = (_Float16)1.0f;
  }

  f16x4 YpA[8], YpB[8];
  #pragma unroll
  for (int t = 0; t < 8; ++t) {
    int gt = g0 + 16 * t;
    YpB[t] = pack4(ldsYp[m * YP_LD + gt + 4 * q + 0],
                   ldsYp[m * YP_LD + gt + 4 * q + 1],
                   ldsYp[m * YP_LD + gt + 4 * q + 2],
                   ldsYp[m * YP_LD + gt + 4 * q + 3]);
    YpA[t] = pack4(ldsYp[(4 * q + 0) * YP_LD + gt + m],
                   ldsYp[(4 * q + 1) * YP_LD + gt + m],
                   ldsYp[(4 * q + 2) * YP_LD + gt + m],
                   ldsYp[(4 * q + 3) * YP_LD + gt + m]);
  }

  // ---- tgt = Uk@Lambda via one MFMA (master layout D[4q+r][m]) ----
  f32x4 tgt;
  {
    f16x4 UkA = pack4(ldsUk[m * 16 + 4 * q + 0], ldsUk[m * 16 + 4 * q + 1],
                      ldsUk[m * 16 + 4 * q + 2], ldsUk[m * 16 + 4 * q + 3]);
    f16x4 LmB = pack4(ldsLm[(4 * q + 0) * 16 + m], ldsLm[(4 * q + 1) * 16 + m],
                      ldsLm[(4 * q + 2) * 16 + m], ldsLm[(4 * q + 3) * 16 + m]);
    f32x4 z = {0.f, 0.f, 0.f, 0.f};
    tgt = __builtin_amdgcn_mfma_f32_16x16x16f16(UkA, LmB, z, 0, 0, 0);
  }

  const int niter = nitp[0];
  const int rslot = lane * 4;
  constexpr float KLAM = -(MUv) * (ROv);   // lamN = -mu*lam master

  // norm-fold: OmPre = Om + u*Om, u = -mu*rsq(n2_row), 3 MFMAs + 1 rsq
  auto norm_fold = [&](const f16x4& omb, const f32x4& om) -> f32x4 {
    f32x4 z = {0.f, 0.f, 0.f, 0.f};
    f16x4 sq = omb * omb;
    f32x4 d1 = __builtin_amdgcn_mfma_f32_16x16x16f16(sq, Ifrag, z, 0, 0, 0);
    f16x4 t1 = pack4(d1[0], d1[1], d1[2], d1[3]);
    f32x4 n2 = __builtin_amdgcn_mfma_f32_16x16x16f16(ones1, t1, z, 0, 0, 0);
    float u  = -MUv * __builtin_amdgcn_rsqf(n2[0]);
    f16x4 uI = Ifrag * pack_dup(u);
    return __builtin_amdgcn_mfma_f32_16x16x16f16(uI, omb, om, 0, 0, 0);
  };

  // ---- prologue round ("iter -1"): P(Om_0); wv0 -> lamN_1 into slot 1 ----
  f16x4 OmB[8];
  #pragma unroll
  for (int t = 0; t < 8; ++t)
    OmB[t] = pack4(Om[t][0], Om[t][1], Om[t][2], Om[t][3]);
  {
    f32x4 a0 = {0.f, 0.f, 0.f, 0.f}, a1 = {0.f, 0.f, 0.f, 0.f};
    #pragma unroll
    for (int t = 0; t < 8; t += 2) {
      a0 = __builtin_amdgcn_mfma_f32_16x16x16f16(YpB[t], OmB[t], a0, 0, 0, 0);
      a1 = __builtin_amdgcn_mfma_f32_16x16x16f16(YpB[t + 1], OmB[t + 1], a1, 0, 0, 0);
    }
    *(f32x4*)&ldsRed[wv][rslot] = a0 + a1;
  }
  __syncthreads();  // b1'

  f32x4 lamM = {0.f, 0.f, 0.f, 0.f};   // wv0: lamN_{i+1} master
  if (wv == 0) {
    f32x4 p[8];
    #pragma unroll
    for (int w2 = 0; w2 < 8; ++w2)
      p[w2] = *(const f32x4*)&ldsRed[w2][rslot];
    f32x4 gsum = ((p[0] + p[1]) + (p[2] + p[3])) + ((p[4] + p[5]) + (p[6] + p[7]));
    f32x4 delta = gsum - tgt;
    #pragma unroll
    for (int e = 0; e < 4; ++e) lamM[e] = KLAM * delta[e];   // lamN_1
    *(f32x4*)&ldsLam[1][rslot] = lamM;
  }
  f32x4 OmPre[8];
  #pragma unroll
  for (int t = 0; t < 8; ++t)
    OmPre[t] = norm_fold(OmB[t], Om[t]);
  __syncthreads();  // b2'

  f16x4 lam_use = pack_dup(0.f);       // lamN_0 = 0

  for (int it = 0; it < niter; ++it) {
    // ===== HOT: Om_{i+1} = OmPre_i + YpT@lamN_i (fused C); phase B =====
    f32x4 a0 = {0.f, 0.f, 0.f, 0.f}, a1 = {0.f, 0.f, 0.f, 0.f};
    #pragma unroll
    for (int t = 0; t < 8; ++t) {
      Om[t]  = __builtin_amdgcn_mfma_f32_16x16x16f16(YpA[t], lam_use, OmPre[t], 0, 0, 0);
      OmB[t] = pack4(Om[t][0], Om[t][1], Om[t][2], Om[t][3]);
      if (t & 1)
        a1 = __builtin_amdgcn_mfma_f32_16x16x16f16(YpB[t], OmB[t], a1, 0, 0, 0);
      else
        a0 = __builtin_amdgcn_mfma_f32_16x16x16f16(YpB[t], OmB[t], a0, 0, 0, 0);
    }
    *(f32x4*)&ldsRed[wv][rslot] = a0 + a1;

    __syncthreads();  // b1

    // ===== GAP: wv0 reduce -> lamN_{i+2}; all: norm-fold -> OmPre_{i+1} =====
    f32x4 lamNew;
    if (wv == 0) {
      f32x4 p[8];
      #pragma unroll
      for (int w2 = 0; w2 < 8; ++w2)
        p[w2] = *(const f32x4*)&ldsRed[w2][rslot];
      f32x4 gsum = ((p[0] + p[1]) + (p[2] + p[3])) + ((p[4] + p[5]) + (p[6] + p[7]));
      f32x4 delta = gsum - tgt;
      #pragma unroll
      for (int e = 0; e < 4; ++e) lamNew[e] = fmaf(KLAM, delta[e], lamM[e]);
      *(f32x4*)&ldsLam[it & 1][rslot] = lamNew;
    }
    #pragma unroll
    for (int t = 0; t < 8; ++t)
      OmPre[t] = norm_fold(OmB[t], Om[t]);

    __syncthreads();  // b2

    // ===== TAIL: pick up lamN_{i+1} for next HOT =====
    if (wv == 0) {
      lam_use = pack4(lamM[0], lamM[1], lamM[2], lamM[3]);
      lamM = lamNew;
    } else {
      f32x4 lr = *(const f32x4*)&ldsLam[(it + 1) & 1][rslot];
      lam_use = pack4(lr[0], lr[1], lr[2], lr[3]);
    }
  }

  // ---- store Omega ----
  float* og = out + (size_t)wb * (G * S);
  #pragma unroll
  for (int t = 0; t < 8; ++t)
    #pragma unroll
    for (int r = 0; r < 4; ++r)
      og[(g0 + 16 * t + 4 * q + r) * S + m] = Om[t][r];
}

extern "C" void kernel_launch(void* const* d_in, const int* in_sizes, int n_in,
                              void* d_out, int out_size, void* d_ws, size_t ws_size,
                              hipStream_t stream) {
  const float* Yp  = (const float*)d_in[0];
  const float* Uk  = (const float*)d_in[1];
  const float* Lm  = (const float*)d_in[2];
  const float* Om0 = (const float*)d_in[3];
  const int*   nit = (const int*)d_in[4];
  float* out = (float*)d_out;

  gd_lagrange_kernel<<<dim3(128), dim3(512), 0, stream>>>(Yp, Uk, Lm, Om0, nit, out);
}